// Round 7
// baseline (33.257 us; speedup 1.0000x reference)
//
#include <hip/hip_runtime.h>

// HungarianMatcher cost matrix:
//   C[n,m] = (1 - sigmoid(cls_boxes[n, cls_targets[m]-1]))      // class cost
//          + sum_k |pred_boxes[n,k] - tgt_boxes[m,k]|           // L1 box cost
//          - IoU(pred_boxes[n], tgt_boxes[m])                   // neg IoU cost
//
// N=16384, M=2048, NCLS=40. Output 128 MiB fp32.
// VALU-minimized form (round 4 showed VALU-issue bound, not store bound):
//   l1 = |x1-x1'|+|x2-x2'|+... = 2*(u+v) + P + T,
//     u = lx-rx, v = ly-ry (reuses the IoU intersection min/max!),
//     P = pred w+h (baked into the LDS sigmoid table, per row),
//     T = tgt  w+h (per-thread register constant).
//   w = max(-u,0), h = max(-v,0)  (neg is a free VOP modifier)
//   union = area1+area2-ov  (>= 1e-4 >> eps, so the eps clamp is dropped)
//   res = fma(-ov, rcp(union), fma(2, u+v, sv + T))
//   => ~15 VALU + 1 trans per element (was ~22 + div).
// __launch_bounds__(256,8): cap 64 VGPR -> 8 waves/SIMD so store-queue and
// LDS latency hide behind other waves. Per-row values (pb, area1) are
// block-uniform -> SGPRs, keeping VGPR pressure low (RG=2 keeps sv at 8).

#define NPRED  16384
#define NTGT   2048
#define NCLS   40
#define NITER  16          // n-rows per block
#define RG     2           // rows per unrolled group
#define MTILES 2           // 2 x 1024 columns
#define BLOCK  256
#define SSTRIDE 20         // floats per class row in ST (16 rows + pad)

typedef float f32x4 __attribute__((ext_vector_type(4)));
typedef float f32x2 __attribute__((ext_vector_type(2)));

__global__ __launch_bounds__(BLOCK, 8) void matcher_cost_kernel(
    const float*  __restrict__ cls_boxes,    // [NPRED, NCLS]
    const int*    __restrict__ cls_targets,  // [NTGT]
    const float4* __restrict__ pred_boxes,   // [NPRED]
    const float4* __restrict__ tgt_boxes,    // [NTGT]
    float* __restrict__ out)                 // [NPRED, NTGT]
{
    __shared__ __align__(16) float ST[NCLS * SSTRIDE];   // 3.2 KB

    const int mtile = blockIdx.x & (MTILES - 1);
    const int ntile = blockIdx.x / MTILES;
    const int n0 = ntile * NITER;

    // ST[c][r] = 1/(1+exp(cls[n0+r][c])) + P[r],  P = pred (w+h) of row r.
    for (int e = threadIdx.x; e < NCLS * NITER; e += BLOCK) {
        int c = e >> 4;            // 0..39 (NITER == 16)
        int r = e & (NITER - 1);   // 0..15
        float4 pb = pred_boxes[n0 + r];                  // L1-hot, 16 rows
        float P = (pb.z - pb.x) + (pb.w - pb.y);
        float x = cls_boxes[(size_t)(n0 + r) * NCLS + c];
        ST[c * SSTRIDE + r] = __builtin_amdgcn_rcpf(1.0f + __expf(x)) + P;
    }

    // Register-cache this thread's 4 consecutive targets.
    const int m4    = mtile * BLOCK + threadIdx.x;   // 0..511
    const int mbase = m4 * 4;
    float4 tb[4];
    float  area2[4], T[4];
    const float* stp[4];
    #pragma unroll
    for (int j = 0; j < 4; ++j) {
        tb[j] = tgt_boxes[mbase + j];
        float tw = tb[j].z - tb[j].x;
        float th = tb[j].w - tb[j].y;
        area2[j] = tw * th;
        T[j]     = tw + th;
        stp[j]   = &ST[(cls_targets[mbase + j] - 1) * SSTRIDE]; // labels 1..N
    }

    __syncthreads();

    float* orow = out + (size_t)n0 * NTGT + mbase;

    #pragma unroll
    for (int g = 0; g < NITER / RG; ++g) {
        // sigmoid(+P) costs for this thread's 4 classes, RG rows: ds_read_b64
        float sv[4][RG];
        #pragma unroll
        for (int j = 0; j < 4; ++j) {
            f32x2 s2 = *reinterpret_cast<const f32x2*>(stp[j] + g * RG);
            sv[j][0] = s2.x; sv[j][1] = s2.y;
        }

        #pragma unroll
        for (int k = 0; k < RG; ++k) {
            const int r = g * RG + k;
            float4 pb = pred_boxes[n0 + r];          // block-uniform -> SGPR
            float area1 = (pb.z - pb.x) * (pb.w - pb.y);

            f32x4 res;
            #pragma unroll
            for (int j = 0; j < 4; ++j) {
                float lx = fmaxf(pb.x, tb[j].x);
                float ly = fmaxf(pb.y, tb[j].y);
                float rx = fminf(pb.z, tb[j].z);
                float ry = fminf(pb.w, tb[j].w);
                float u  = lx - rx;
                float v  = ly - ry;
                float w  = fmaxf(-u, 0.0f);          // neg modifier, free
                float h  = fmaxf(-v, 0.0f);
                float ov = w * h;
                float uni = (area1 + area2[j]) - ov; // >= 1e-4, eps clamp moot
                float rc  = __builtin_amdgcn_rcpf(uni);
                float base = fmaf(2.0f, u + v, sv[j][k] + T[j]); // class+L1
                res[j] = fmaf(-ov, rc, base);                    // - IoU
            }
            *reinterpret_cast<f32x4*>(orow + (size_t)r * NTGT) = res;
        }
    }
}

extern "C" void kernel_launch(void* const* d_in, const int* in_sizes, int n_in,
                              void* d_out, int out_size, void* d_ws, size_t ws_size,
                              hipStream_t stream) {
    const float*  cls_boxes   = (const float*)d_in[0];
    const int*    cls_targets = (const int*)d_in[1];
    const float4* pred_boxes  = (const float4*)d_in[2];
    const float4* tgt_boxes   = (const float4*)d_in[3];
    float* out = (float*)d_out;

    const int grid = MTILES * (NPRED / NITER);   // 2048 blocks
    matcher_cost_kernel<<<grid, BLOCK, 0, stream>>>(
        cls_boxes, cls_targets, pred_boxes, tgt_boxes, out);
}

// Round 8
// 33.194 us; speedup vs baseline: 1.0019x; 1.0019x over previous
//
#include <hip/hip_runtime.h>

// HungarianMatcher cost matrix:
//   C[n,m] = (1 - sigmoid(cls_boxes[n, cls_targets[m]-1]))      // class cost
//          + sum_k |pred_boxes[n,k] - tgt_boxes[m,k]|           // L1 box cost
//          - IoU(pred_boxes[n], tgt_boxes[m])                   // neg IoU cost
//
// N=16384, M=2048, NCLS=40. Output 128 MiB fp32.
// VALU-minimized form (round 4 showed VALU-issue bound, not store bound):
//   l1 = |x1-x1'|+|x2-x2'|+... = 2*(u+v) + P + T,
//     u = lx-rx, v = ly-ry (reuses the IoU intersection min/max!),
//     P = pred w+h (baked into the LDS sigmoid table, per row),
//     T = tgt  w+h (per-thread register constant).
//   w = max(-u,0), h = max(-v,0)  (neg is a free VOP modifier)
//   union = area1+area2-ov  (>= 1e-4 >> eps, so the eps clamp is dropped)
//   res = fma(-ov, rcp(union), fma(2, u+v, sv + T))
//   => ~15 VALU + 1 trans per element (was ~22 + div).
// __launch_bounds__(256,8): cap 64 VGPR -> 8 waves/SIMD so store-queue and
// LDS latency hide behind other waves. Per-row values (pb, area1) are
// block-uniform -> SGPRs, keeping VGPR pressure low (RG=2 keeps sv at 8).

#define NPRED  16384
#define NTGT   2048
#define NCLS   40
#define NITER  16          // n-rows per block
#define RG     2           // rows per unrolled group
#define MTILES 2           // 2 x 1024 columns
#define BLOCK  256
#define SSTRIDE 20         // floats per class row in ST (16 rows + pad)

typedef float f32x4 __attribute__((ext_vector_type(4)));
typedef float f32x2 __attribute__((ext_vector_type(2)));

__global__ __launch_bounds__(BLOCK, 8) void matcher_cost_kernel(
    const float*  __restrict__ cls_boxes,    // [NPRED, NCLS]
    const int*    __restrict__ cls_targets,  // [NTGT]
    const float4* __restrict__ pred_boxes,   // [NPRED]
    const float4* __restrict__ tgt_boxes,    // [NTGT]
    float* __restrict__ out)                 // [NPRED, NTGT]
{
    __shared__ __align__(16) float ST[NCLS * SSTRIDE];   // 3.2 KB

    const int mtile = blockIdx.x & (MTILES - 1);
    const int ntile = blockIdx.x / MTILES;
    const int n0 = ntile * NITER;

    // ST[c][r] = 1/(1+exp(cls[n0+r][c])) + P[r],  P = pred (w+h) of row r.
    for (int e = threadIdx.x; e < NCLS * NITER; e += BLOCK) {
        int c = e >> 4;            // 0..39 (NITER == 16)
        int r = e & (NITER - 1);   // 0..15
        float4 pb = pred_boxes[n0 + r];                  // L1-hot, 16 rows
        float P = (pb.z - pb.x) + (pb.w - pb.y);
        float x = cls_boxes[(size_t)(n0 + r) * NCLS + c];
        ST[c * SSTRIDE + r] = __builtin_amdgcn_rcpf(1.0f + __expf(x)) + P;
    }

    // Register-cache this thread's 4 consecutive targets.
    const int m4    = mtile * BLOCK + threadIdx.x;   // 0..511
    const int mbase = m4 * 4;
    float4 tb[4];
    float  area2[4], T[4];
    const float* stp[4];
    #pragma unroll
    for (int j = 0; j < 4; ++j) {
        tb[j] = tgt_boxes[mbase + j];
        float tw = tb[j].z - tb[j].x;
        float th = tb[j].w - tb[j].y;
        area2[j] = tw * th;
        T[j]     = tw + th;
        stp[j]   = &ST[(cls_targets[mbase + j] - 1) * SSTRIDE]; // labels 1..N
    }

    __syncthreads();

    float* orow = out + (size_t)n0 * NTGT + mbase;

    #pragma unroll
    for (int g = 0; g < NITER / RG; ++g) {
        // sigmoid(+P) costs for this thread's 4 classes, RG rows: ds_read_b64
        float sv[4][RG];
        #pragma unroll
        for (int j = 0; j < 4; ++j) {
            f32x2 s2 = *reinterpret_cast<const f32x2*>(stp[j] + g * RG);
            sv[j][0] = s2.x; sv[j][1] = s2.y;
        }

        #pragma unroll
        for (int k = 0; k < RG; ++k) {
            const int r = g * RG + k;
            float4 pb = pred_boxes[n0 + r];          // block-uniform -> SGPR
            float area1 = (pb.z - pb.x) * (pb.w - pb.y);

            f32x4 res;
            #pragma unroll
            for (int j = 0; j < 4; ++j) {
                float lx = fmaxf(pb.x, tb[j].x);
                float ly = fmaxf(pb.y, tb[j].y);
                float rx = fminf(pb.z, tb[j].z);
                float ry = fminf(pb.w, tb[j].w);
                float u  = lx - rx;
                float v  = ly - ry;
                float w  = fmaxf(-u, 0.0f);          // neg modifier, free
                float h  = fmaxf(-v, 0.0f);
                float ov = w * h;
                float uni = (area1 + area2[j]) - ov; // >= 1e-4, eps clamp moot
                float rc  = __builtin_amdgcn_rcpf(uni);
                float base = fmaf(2.0f, u + v, sv[j][k] + T[j]); // class+L1
                res[j] = fmaf(-ov, rc, base);                    // - IoU
            }
            *reinterpret_cast<f32x4*>(orow + (size_t)r * NTGT) = res;
        }
    }
}

extern "C" void kernel_launch(void* const* d_in, const int* in_sizes, int n_in,
                              void* d_out, int out_size, void* d_ws, size_t ws_size,
                              hipStream_t stream) {
    const float*  cls_boxes   = (const float*)d_in[0];
    const int*    cls_targets = (const int*)d_in[1];
    const float4* pred_boxes  = (const float4*)d_in[2];
    const float4* tgt_boxes   = (const float4*)d_in[3];
    float* out = (float*)d_out;

    const int grid = MTILES * (NPRED / NITER);   // 2048 blocks
    matcher_cost_kernel<<<grid, BLOCK, 0, stream>>>(
        cls_boxes, cls_targets, pred_boxes, tgt_boxes, out);
}

// Round 9
// 31.102 us; speedup vs baseline: 1.0693x; 1.0673x over previous
//
#include <hip/hip_runtime.h>

// HungarianMatcher cost matrix:
//   C[n,m] = (1 - sigmoid(cls_boxes[n, cls_targets[m]-1]))      // class cost
//          + sum_k |pred_boxes[n,k] - tgt_boxes[m,k]|           // L1 box cost
//          - IoU(pred_boxes[n], tgt_boxes[m])                   // neg IoU cost
//
// N=16384, M=2048, NCLS=40. Output 128 MiB fp32 -> WRITE-PATH bound.
// Round-8 counters: VALUBusy ~2% -> compute is irrelevant; 150 MB HBM in
// 33 us = 4.5 TB/s vs 6.8 TB/s fill rate on the same buffer. Suspect: 2048
// blocks each streaming a scattered 16-row x 4KB column-stripe (2048-way
// interleaved write streams). This round: each block owns one CONTIGUOUS
// 128 KB slab (512 threads x 4 cols = full 2048-col row; 16 consecutive
// rows), stores in ascending address order. Grid 1024 = 4 blocks/CU,
// 32 waves/CU at VGPR<=64.
//
// Math (proven cheap & correct, absmax 0.0156 vs 0.078 threshold):
//   l1 = 2*(u+v) + P + T with u=lx-rx, v=ly-ry reusing IoU min/max,
//   P (pred w+h) baked into LDS sigmoid table, T (tgt w+h) in registers,
//   union eps-clamp dropped (union >= 1e-4 >> 1e-6),
//   rcp via v_rcp_f32 (1 ulp).

#define NPRED  16384
#define NTGT   2048
#define NCLS   40
#define NITER  16          // consecutive n-rows per block
#define RG     2           // rows per unrolled group (ds_read_b64)
#define BLOCK  512         // 512 threads x 4 cols = full row
#define SSTRIDE 20         // floats per class row in ST (16 rows + pad)

typedef float f32x4 __attribute__((ext_vector_type(4)));
typedef float f32x2 __attribute__((ext_vector_type(2)));

__global__ __launch_bounds__(BLOCK, 8) void matcher_cost_kernel(
    const float*  __restrict__ cls_boxes,    // [NPRED, NCLS]
    const int*    __restrict__ cls_targets,  // [NTGT]
    const float4* __restrict__ pred_boxes,   // [NPRED]
    const float4* __restrict__ tgt_boxes,    // [NTGT]
    float* __restrict__ out)                 // [NPRED, NTGT]
{
    __shared__ __align__(16) float ST[NCLS * SSTRIDE];   // 3.2 KB

    const int n0 = blockIdx.x * NITER;

    // ST[c][r] = 1/(1+exp(cls[n0+r][c])) + P[r],  P = pred (w+h) of row r.
    for (int e = threadIdx.x; e < NCLS * NITER; e += BLOCK) {
        int c = e >> 4;            // 0..39 (NITER == 16)
        int r = e & (NITER - 1);   // 0..15
        float4 pb = pred_boxes[n0 + r];                  // L1-hot, 16 rows
        float P = (pb.z - pb.x) + (pb.w - pb.y);
        float x = cls_boxes[(size_t)(n0 + r) * NCLS + c];
        ST[c * SSTRIDE + r] = __builtin_amdgcn_rcpf(1.0f + __expf(x)) + P;
    }

    // Register-cache this thread's 4 consecutive targets.
    const int mbase = threadIdx.x * 4;               // 0..2044
    float4 tb[4];
    float  area2[4], T[4];
    const float* stp[4];
    #pragma unroll
    for (int j = 0; j < 4; ++j) {
        tb[j] = tgt_boxes[mbase + j];
        float tw = tb[j].z - tb[j].x;
        float th = tb[j].w - tb[j].y;
        area2[j] = tw * th;
        T[j]     = tw + th;
        stp[j]   = &ST[(cls_targets[mbase + j] - 1) * SSTRIDE]; // labels 1..N
    }

    __syncthreads();

    float* orow = out + (size_t)n0 * NTGT + mbase;

    #pragma unroll
    for (int g = 0; g < NITER / RG; ++g) {
        // class(+P) costs for this thread's 4 classes, RG rows
        float sv[4][RG];
        #pragma unroll
        for (int j = 0; j < 4; ++j) {
            f32x2 s2 = *reinterpret_cast<const f32x2*>(stp[j] + g * RG);
            sv[j][0] = s2.x; sv[j][1] = s2.y;
        }

        #pragma unroll
        for (int k = 0; k < RG; ++k) {
            const int r = g * RG + k;
            float4 pb = pred_boxes[n0 + r];          // block-uniform -> SGPR
            float area1 = (pb.z - pb.x) * (pb.w - pb.y);

            f32x4 res;
            #pragma unroll
            for (int j = 0; j < 4; ++j) {
                float lx = fmaxf(pb.x, tb[j].x);
                float ly = fmaxf(pb.y, tb[j].y);
                float rx = fminf(pb.z, tb[j].z);
                float ry = fminf(pb.w, tb[j].w);
                float u  = lx - rx;
                float v  = ly - ry;
                float w  = fmaxf(-u, 0.0f);          // neg modifier, free
                float h  = fmaxf(-v, 0.0f);
                float ov = w * h;
                float uni = (area1 + area2[j]) - ov; // >= 1e-4, eps moot
                float rc  = __builtin_amdgcn_rcpf(uni);
                float base = fmaf(2.0f, u + v, sv[j][k] + T[j]); // cls + L1
                res[j] = fmaf(-ov, rc, base);                    // - IoU
            }
            *reinterpret_cast<f32x4*>(orow + (size_t)r * NTGT) = res;
        }
    }
}

extern "C" void kernel_launch(void* const* d_in, const int* in_sizes, int n_in,
                              void* d_out, int out_size, void* d_ws, size_t ws_size,
                              hipStream_t stream) {
    const float*  cls_boxes   = (const float*)d_in[0];
    const int*    cls_targets = (const int*)d_in[1];
    const float4* pred_boxes  = (const float4*)d_in[2];
    const float4* tgt_boxes   = (const float4*)d_in[3];
    float* out = (float*)d_out;

    const int grid = NPRED / NITER;   // 1024 blocks, contiguous 128 KB slabs
    matcher_cost_kernel<<<grid, BLOCK, 0, stream>>>(
        cls_boxes, cls_targets, pred_boxes, tgt_boxes, out);
}